// Round 4
// baseline (641.461 us; speedup 1.0000x reference)
//
#include <hip/hip_runtime.h>

typedef short bf16x8 __attribute__((ext_vector_type(8)));
typedef float f32x4 __attribute__((ext_vector_type(4)));
typedef unsigned short u16;
typedef unsigned int u32;

static __device__ __forceinline__ u16 f2bf(float f) {
  u32 u = __builtin_bit_cast(u32, f);
  u32 r = (u + 0x7FFFu + ((u >> 16) & 1u)) >> 16;  // RNE
  return (u16)r;
}

// LDS layout (u16 units):
//  [0, 16896)        X [64 pos][264]   (phase 1-2)  -- reused as P: 4 waves x [64][72] (phase 3)
//  [18432, 51712)    QK [64 pos][520]  cols 0..255 = Q (later O), 256..511 = K
//  [51712, 70144)    VT [256 hd][72]   V transposed
#define XP_OFF 0
#define QK_OFF 18432
#define VT_OFF 51712
#define LDS_TOT 70144  // 140288 B < 160 KiB

__global__ __launch_bounds__(256) void k_fused(
    const float* __restrict__ x, const float* __restrict__ wqkv,
    const float* __restrict__ wproj, const int* __restrict__ shiftp,
    float* __restrict__ out) {
  __shared__ u16 LDS[LDS_TOT];
  const int win = blockIdx.x;                 // b*64 + wh*8 + ww
  const int b = win >> 6, wh = (win >> 3) & 7, ww = win & 7;
  const int off = (shiftp[0] != 0) ? 4 : 0;   // robust: int 1 or f32 1.0 both nonzero
  const int t = threadIdx.x;

  // ---- phase 1: stage rolled X into LDS [pos][c], f32 -> bf16 ----
  {
    u16* X = LDS + XP_OFF;
    const int wr = t & 7;
    const int h = ((wh << 3) + wr + off) & 63;
    const int w0 = ((ww << 3) + off) & 63;     // 4-aligned -> no wrap inside run
    const int w1 = ((ww << 3) + off + 4) & 63;
    const int p0 = wr << 3;
    for (int it = 0; it < 8; ++it) {
      const int c = (t >> 3) + (it << 5);
      const float* src = x + ((size_t)(b * 256 + c) * 64 + h) * 64;
      float4 v0 = *(const float4*)(src + w0);
      float4 v1 = *(const float4*)(src + w1);
      X[(p0 + 0) * 264 + c] = f2bf(v0.x);
      X[(p0 + 1) * 264 + c] = f2bf(v0.y);
      X[(p0 + 2) * 264 + c] = f2bf(v0.z);
      X[(p0 + 3) * 264 + c] = f2bf(v0.w);
      X[(p0 + 4) * 264 + c] = f2bf(v1.x);
      X[(p0 + 5) * 264 + c] = f2bf(v1.y);
      X[(p0 + 6) * 264 + c] = f2bf(v1.z);
      X[(p0 + 7) * 264 + c] = f2bf(v1.w);
    }
  }
  __syncthreads();

  const int lane = t & 63, wv = t >> 6;        // wave wv owns m-rows wv*16..+15
  const int l15 = lane & 15, quad = lane >> 4;

  // ---- phase 2: QKV = X * Wqkv^T, results into LDS ----
  bf16x8 af[8];
  {
    const u16* ar = LDS + XP_OFF + (wv * 16 + l15) * 264 + quad * 8;
#pragma unroll
    for (int k = 0; k < 8; ++k) af[k] = *(const bf16x8*)(ar + k * 32);
  }
  const int pos0 = wv * 16 + quad * 4;
#pragma unroll 1
  for (int nt = 0; nt < 48; ++nt) {
    f32x4 acc = {0.f, 0.f, 0.f, 0.f};
    const float* br = wqkv + (size_t)(nt * 16 + l15) * 256 + quad * 8;
#pragma unroll
    for (int k = 0; k < 8; ++k) {
      float4 f0 = *(const float4*)(br + k * 32);
      float4 f1 = *(const float4*)(br + k * 32 + 4);
      bf16x8 bf;
      bf[0] = (short)f2bf(f0.x); bf[1] = (short)f2bf(f0.y);
      bf[2] = (short)f2bf(f0.z); bf[3] = (short)f2bf(f0.w);
      bf[4] = (short)f2bf(f1.x); bf[5] = (short)f2bf(f1.y);
      bf[6] = (short)f2bf(f1.z); bf[7] = (short)f2bf(f1.w);
      acc = __builtin_amdgcn_mfma_f32_16x16x32_bf16(af[k], bf, acc, 0, 0, 0);
    }
    const int o = nt * 16 + l15;               // 0..767
    if (o < 512) {                             // Q or K -> QK[pos][o]
#pragma unroll
      for (int r = 0; r < 4; ++r) LDS[QK_OFF + (pos0 + r) * 520 + o] = f2bf(acc[r]);
    } else {                                   // V -> VT[o-512][pos] (transposed)
      ushort4 pk;
      pk.x = f2bf(acc[0]); pk.y = f2bf(acc[1]);
      pk.z = f2bf(acc[2]); pk.w = f2bf(acc[3]);
      *(ushort4*)&LDS[VT_OFF + (o - 512) * 72 + pos0] = pk;
    }
  }
  __syncthreads();

  // ---- phase 3: attention; wave wv handles heads wv and wv+4 ----
  u16* P = LDS + XP_OFF + wv * 4608;           // per-wave [64][72]
  const float scale = 0.17677669529663687f;    // 1/sqrt(32)
#pragma unroll 1
  for (int hh = 0; hh < 2; ++hh) {
    const int head = wv + hh * 4;
    bf16x8 aq[4], bk[4];
#pragma unroll
    for (int i = 0; i < 4; ++i) {
      aq[i] = *(const bf16x8*)&LDS[QK_OFF + (i * 16 + l15) * 520 + head * 32 + quad * 8];
      bk[i] = *(const bf16x8*)&LDS[QK_OFF + (i * 16 + l15) * 520 + 256 + head * 32 + quad * 8];
    }
    f32x4 sc[4][4];
#pragma unroll
    for (int mt = 0; mt < 4; ++mt)
#pragma unroll
      for (int nt = 0; nt < 4; ++nt) {
        f32x4 z = {0.f, 0.f, 0.f, 0.f};
        sc[mt][nt] = __builtin_amdgcn_mfma_f32_16x16x32_bf16(aq[mt], bk[nt], z, 0, 0, 0);
      }
#pragma unroll
    for (int mt = 0; mt < 4; ++mt) {
#pragma unroll
      for (int r = 0; r < 4; ++r) {
        float mx = -1e30f;
#pragma unroll
        for (int nt = 0; nt < 4; ++nt) mx = fmaxf(mx, sc[mt][nt][r]);
        mx = fmaxf(mx, __shfl_xor(mx, 1));
        mx = fmaxf(mx, __shfl_xor(mx, 2));
        mx = fmaxf(mx, __shfl_xor(mx, 4));
        mx = fmaxf(mx, __shfl_xor(mx, 8));     // row spans the 16-lane group
        float p[4], sum = 0.f;
#pragma unroll
        for (int nt = 0; nt < 4; ++nt) {
          p[nt] = __expf((sc[mt][nt][r] - mx) * scale);
          sum += p[nt];
        }
        sum += __shfl_xor(sum, 1);
        sum += __shfl_xor(sum, 2);
        sum += __shfl_xor(sum, 4);
        sum += __shfl_xor(sum, 8);
        const float is = 1.f / sum;
        const int row = mt * 16 + quad * 4 + r;  // C/D -> [row][col] in LDS
#pragma unroll
        for (int nt = 0; nt < 4; ++nt) P[row * 72 + nt * 16 + l15] = f2bf(p[nt] * is);
      }
    }
    // PV (per-wave P region; in-wave LDS ordering suffices)
    f32x4 oa[4][2];
#pragma unroll
    for (int mt = 0; mt < 4; ++mt)
#pragma unroll
      for (int nt = 0; nt < 2; ++nt) oa[mt][nt] = (f32x4){0.f, 0.f, 0.f, 0.f};
#pragma unroll
    for (int kk = 0; kk < 2; ++kk) {
      bf16x8 bv[2];
#pragma unroll
      for (int nt = 0; nt < 2; ++nt)
        bv[nt] = *(const bf16x8*)&LDS[VT_OFF + (head * 32 + nt * 16 + l15) * 72 + kk * 32 + quad * 8];
#pragma unroll
      for (int mt = 0; mt < 4; ++mt) {
        bf16x8 ap = *(const bf16x8*)&P[(mt * 16 + l15) * 72 + kk * 32 + quad * 8];
#pragma unroll
        for (int nt = 0; nt < 2; ++nt)
          oa[mt][nt] = __builtin_amdgcn_mfma_f32_16x16x32_bf16(ap, bv[nt], oa[mt][nt], 0, 0, 0);
      }
    }
    // O overwrites own head's Q columns: QK[pos][head*32+hd]
#pragma unroll
    for (int mt = 0; mt < 4; ++mt)
#pragma unroll
      for (int nt = 0; nt < 2; ++nt)
#pragma unroll
        for (int r = 0; r < 4; ++r) {
          const int pos = mt * 16 + quad * 4 + r;
          LDS[QK_OFF + pos * 520 + head * 32 + nt * 16 + l15] = f2bf(oa[mt][nt][r]);
        }
  }
  __syncthreads();

  // ---- phase 4: out = O * Wproj^T, fused roll(+4,+4), f32 stores ----
  bf16x8 ao[8];
  {
    const u16* ar = &LDS[QK_OFF + (wv * 16 + l15) * 520 + quad * 8];
#pragma unroll
    for (int k = 0; k < 8; ++k) ao[k] = *(const bf16x8*)(ar + k * 32);
  }
  const int h = ((wh << 3) + (pos0 >> 3) + off) & 63;
  const int w0 = ((ww << 3) + (pos0 & 7) + off) & 63;  // 4-aligned run, no wrap
#pragma unroll 1
  for (int nt = 0; nt < 16; ++nt) {
    f32x4 acc = {0.f, 0.f, 0.f, 0.f};
    const float* br = wproj + (size_t)(nt * 16 + l15) * 256 + quad * 8;
#pragma unroll
    for (int k = 0; k < 8; ++k) {
      float4 f0 = *(const float4*)(br + k * 32);
      float4 f1 = *(const float4*)(br + k * 32 + 4);
      bf16x8 bf;
      bf[0] = (short)f2bf(f0.x); bf[1] = (short)f2bf(f0.y);
      bf[2] = (short)f2bf(f0.z); bf[3] = (short)f2bf(f0.w);
      bf[4] = (short)f2bf(f1.x); bf[5] = (short)f2bf(f1.y);
      bf[6] = (short)f2bf(f1.z); bf[7] = (short)f2bf(f1.w);
      acc = __builtin_amdgcn_mfma_f32_16x16x32_bf16(ao[k], bf, acc, 0, 0, 0);
    }
    const int c = nt * 16 + l15;
    float4 pk;
    pk.x = acc[0]; pk.y = acc[1]; pk.z = acc[2]; pk.w = acc[3];
    *(float4*)&out[((size_t)(b * 256 + c) << 12) + (h << 6) + w0] = pk;
  }
}

extern "C" void kernel_launch(void* const* d_in, const int* in_sizes, int n_in,
                              void* d_out, int out_size, void* d_ws, size_t ws_size,
                              hipStream_t stream) {
  const float* x = (const float*)d_in[0];      // [16,256,64,64] f32
  const float* wqkv = (const float*)d_in[1];   // [768,256] f32
  const float* wproj = (const float*)d_in[2];  // [256,256] f32
  const int* shiftp = (const int*)d_in[3];     // scalar
  float* outp = (float*)d_out;                 // [16,256,64,64] f32
  (void)d_ws; (void)ws_size;                   // zero-workspace design
  hipLaunchKernelGGL(k_fused, dim3(1024), dim3(256), 0, stream,
                     x, wqkv, wproj, shiftp, outp);
}

// Round 5
// 455.312 us; speedup vs baseline: 1.4088x; 1.4088x over previous
//
#include <hip/hip_runtime.h>

typedef short bf16x8 __attribute__((ext_vector_type(8)));
typedef float f32x4 __attribute__((ext_vector_type(4)));
typedef unsigned short u16;
typedef unsigned int u32;

static __device__ __forceinline__ u16 f2bf(float f) {
  u32 u = __builtin_bit_cast(u32, f);
  u32 r = (u + 0x7FFFu + ((u >> 16) & 1u)) >> 16;  // RNE
  return (u16)r;
}

// ---- kernel 0: one-time f32 -> bf16 weight conversion into d_ws ----
// wbf[0..196608) = wqkv, wbf[196608..262144) = wproj
__global__ __launch_bounds__(256) void k_conv(
    const float* __restrict__ wqkv, const float* __restrict__ wproj,
    u16* __restrict__ wbf) {
  const int idx = (blockIdx.x * 256 + threadIdx.x) * 4;  // 256 blocks -> 262144
  float4 v;
  if (idx < 196608) v = *(const float4*)(wqkv + idx);
  else              v = *(const float4*)(wproj + (idx - 196608));
  ushort4 o;
  o.x = f2bf(v.x); o.y = f2bf(v.y); o.z = f2bf(v.z); o.w = f2bf(v.w);
  *(ushort4*)(wbf + idx) = o;
}

// LDS (u16 units). X [64][264] = 16896 lives first; after af-fragments are in
// registers (barrier), the SAME region is reused per-head:
//   QH  = 0      : Qh [64][40]   (rows are per-wave private; O overwrites Q)
//   KH  = 2560   : Kh [64][40]
//   VTH = 5120   : VTh [32][72]  (V transposed: [hd][pos])
//   PH  = 7424   : P, per-wave [16][72] at PH + wv*1152
#define QH 0
#define KH 2560
#define VTH 5120
#define PH 7424
#define LDS_TOT 16896  // 33.8 KB -> 3 blocks/CU (VGPR-capped)

__global__ __launch_bounds__(256, 3) void k_fused(
    const float* __restrict__ x, const u16* __restrict__ wbf,
    const int* __restrict__ shiftp, float* __restrict__ out) {
  __shared__ u16 LDS[LDS_TOT];
  const u16* wqkv_bf = wbf;            // [768][256]
  const u16* wproj_bf = wbf + 196608;  // [256][256]
  const int win = blockIdx.x;          // b*64 + wh*8 + ww
  const int b = win >> 6, wh = (win >> 3) & 7, ww = win & 7;
  const int off = (shiftp[0] != 0) ? 4 : 0;
  const int t = threadIdx.x;

  // ---- phase 1: stage rolled X into LDS [pos][c] (f32 -> bf16) ----
  {
    u16* X = LDS;
    const int wr = t & 7;
    const int h = ((wh << 3) + wr + off) & 63;
    const int w0 = ((ww << 3) + off) & 63;   // 4-aligned -> no wrap inside run
    const int w1 = ((ww << 3) + off + 4) & 63;
    const int p0 = wr << 3;
    for (int it = 0; it < 8; ++it) {
      const int c = (t >> 3) + (it << 5);
      const float* src = x + ((size_t)(b * 256 + c) * 64 + h) * 64;
      float4 v0 = *(const float4*)(src + w0);
      float4 v1 = *(const float4*)(src + w1);
      X[(p0 + 0) * 264 + c] = f2bf(v0.x);
      X[(p0 + 1) * 264 + c] = f2bf(v0.y);
      X[(p0 + 2) * 264 + c] = f2bf(v0.z);
      X[(p0 + 3) * 264 + c] = f2bf(v0.w);
      X[(p0 + 4) * 264 + c] = f2bf(v1.x);
      X[(p0 + 5) * 264 + c] = f2bf(v1.y);
      X[(p0 + 6) * 264 + c] = f2bf(v1.z);
      X[(p0 + 7) * 264 + c] = f2bf(v1.w);
    }
  }
  __syncthreads();

  const int lane = t & 63, wv = t >> 6;  // wave wv owns pos rows wv*16..+15
  const int l15 = lane & 15, quad = lane >> 4;
  const int pos0 = wv * 16 + quad * 4;

  // A-fragments of X for this wave's pos-tile (verified round-4 pattern)
  bf16x8 af[8];
#pragma unroll
  for (int k = 0; k < 8; ++k)
    af[k] = *(const bf16x8*)&LDS[(wv * 16 + l15) * 264 + quad * 8 + k * 32];
  __syncthreads();  // X dead; region reused below

  f32x4 accP[16];   // proj accumulators: c_out tile mt, rows quad*4+r, col pos=l15
#pragma unroll
  for (int mt = 0; mt < 16; ++mt) accP[mt] = (f32x4){0.f, 0.f, 0.f, 0.f};

  const float scale = 0.17677669529663687f;  // 1/sqrt(32)
  u16* Pw = LDS + PH + wv * 1152;            // per-wave P [16][72]

#pragma unroll 1
  for (int h = 0; h < 8; ++h) {
    // ---- QKV GEMM for this head: 6 output tiles (Q,K,V x 2) ----
#pragma unroll
    for (int s = 0; s < 3; ++s) {
#pragma unroll
      for (int u = 0; u < 2; ++u) {
        f32x4 acc = {0.f, 0.f, 0.f, 0.f};
        const u16* br = wqkv_bf + (size_t)(s * 256 + h * 32 + u * 16 + l15) * 256 + quad * 8;
#pragma unroll
        for (int k = 0; k < 8; ++k)
          acc = __builtin_amdgcn_mfma_f32_16x16x32_bf16(af[k], *(const bf16x8*)(br + k * 32), acc, 0, 0, 0);
        if (s == 0) {
#pragma unroll
          for (int r = 0; r < 4; ++r)
            LDS[QH + (pos0 + r) * 40 + u * 16 + l15] = f2bf(acc[r]);
        } else if (s == 1) {
#pragma unroll
          for (int r = 0; r < 4; ++r)
            LDS[KH + (pos0 + r) * 40 + u * 16 + l15] = f2bf(acc[r]);
        } else {  // V transposed [hd][pos], packed 8B store
          ushort4 pk;
          pk.x = f2bf(acc[0]); pk.y = f2bf(acc[1]);
          pk.z = f2bf(acc[2]); pk.w = f2bf(acc[3]);
          *(ushort4*)&LDS[VTH + (u * 16 + l15) * 72 + pos0] = pk;
        }
      }
    }
    __syncthreads();  // Kh/VTh cross-wave visibility

    // ---- attention: wave handles its own 16 pos rows ----
    bf16x8 aq = *(const bf16x8*)&LDS[QH + (wv * 16 + l15) * 40 + quad * 8];
    f32x4 sc[4];
#pragma unroll
    for (int nt = 0; nt < 4; ++nt) {
      bf16x8 bk = *(const bf16x8*)&LDS[KH + (nt * 16 + l15) * 40 + quad * 8];
      f32x4 z = {0.f, 0.f, 0.f, 0.f};
      sc[nt] = __builtin_amdgcn_mfma_f32_16x16x32_bf16(aq, bk, z, 0, 0, 0);
    }
#pragma unroll
    for (int r = 0; r < 4; ++r) {
      float mx = -1e30f;
#pragma unroll
      for (int nt = 0; nt < 4; ++nt) mx = fmaxf(mx, sc[nt][r]);
      mx = fmaxf(mx, __shfl_xor(mx, 1));
      mx = fmaxf(mx, __shfl_xor(mx, 2));
      mx = fmaxf(mx, __shfl_xor(mx, 4));
      mx = fmaxf(mx, __shfl_xor(mx, 8));  // row spans the 16-lane group
      float p[4], sum = 0.f;
#pragma unroll
      for (int nt = 0; nt < 4; ++nt) {
        p[nt] = __expf((sc[nt][r] - mx) * scale);
        sum += p[nt];
      }
      sum += __shfl_xor(sum, 1);
      sum += __shfl_xor(sum, 2);
      sum += __shfl_xor(sum, 4);
      sum += __shfl_xor(sum, 8);
      const float is = 1.f / sum;
#pragma unroll
      for (int nt = 0; nt < 4; ++nt)
        Pw[(quad * 4 + r) * 72 + nt * 16 + l15] = f2bf(p[nt] * is);
    }
    // PV: O[pos][hd] for this wave's rows
    f32x4 oa[2];
    oa[0] = (f32x4){0.f, 0.f, 0.f, 0.f};
    oa[1] = (f32x4){0.f, 0.f, 0.f, 0.f};
#pragma unroll
    for (int kk = 0; kk < 2; ++kk) {
      bf16x8 ap = *(const bf16x8*)&Pw[l15 * 72 + kk * 32 + quad * 8];
#pragma unroll
      for (int n2 = 0; n2 < 2; ++n2) {
        bf16x8 bv = *(const bf16x8*)&LDS[VTH + (n2 * 16 + l15) * 72 + kk * 32 + quad * 8];
        oa[n2] = __builtin_amdgcn_mfma_f32_16x16x32_bf16(ap, bv, oa[n2], 0, 0, 0);
      }
    }
    // O overwrites own Q rows (wave-private; Q already consumed into aq)
#pragma unroll
    for (int n2 = 0; n2 < 2; ++n2)
#pragma unroll
      for (int r = 0; r < 4; ++r)
        LDS[QH + (pos0 + r) * 40 + n2 * 16 + l15] = f2bf(oa[n2][r]);
    // proj accumulate: A = Wproj rows (c_out), B = O rows (pos), K = 32 (this head)
    bf16x8 bo = *(const bf16x8*)&LDS[QH + (wv * 16 + l15) * 40 + quad * 8];
#pragma unroll
    for (int mt = 0; mt < 16; ++mt) {
      bf16x8 aw = *(const bf16x8*)(wproj_bf + (size_t)(mt * 16 + l15) * 256 + h * 32 + quad * 8);
      accP[mt] = __builtin_amdgcn_mfma_f32_16x16x32_bf16(aw, bo, accP[mt], 0, 0, 0);
    }
    __syncthreads();  // protect Kh/VTh before next head's writes
  }

  // ---- epilogue: C[c_out][pos] -> out[b][c][h][w] with roll(+4,+4) ----
  const int pos = wv * 16 + l15;
  const int hco = ((wh << 3) + (pos >> 3) + off) & 63;
  const int wco = ((ww << 3) + (pos & 7) + off) & 63;
#pragma unroll
  for (int mt = 0; mt < 16; ++mt)
#pragma unroll
    for (int r = 0; r < 4; ++r) {
      const int c = mt * 16 + quad * 4 + r;
      out[((size_t)(b * 256 + c) << 12) + (hco << 6) + wco] = accP[mt][r];
    }
}

extern "C" void kernel_launch(void* const* d_in, const int* in_sizes, int n_in,
                              void* d_out, int out_size, void* d_ws, size_t ws_size,
                              hipStream_t stream) {
  const float* x = (const float*)d_in[0];      // [16,256,64,64] f32
  const float* wqkv = (const float*)d_in[1];   // [768,256] f32
  const float* wproj = (const float*)d_in[2];  // [256,256] f32
  const int* shiftp = (const int*)d_in[3];     // scalar
  float* outp = (float*)d_out;                 // [16,256,64,64] f32
  u16* wbf = (u16*)d_ws;                       // 262144 u16 = 512 KB scratch
  hipLaunchKernelGGL(k_conv, dim3(256), dim3(256), 0, stream, wqkv, wproj, wbf);
  hipLaunchKernelGGL(k_fused, dim3(1024), dim3(256), 0, stream, x, wbf, shiftp, outp);
}

// Round 6
// 436.094 us; speedup vs baseline: 1.4709x; 1.0441x over previous
//
#include <hip/hip_runtime.h>

typedef short bf16x8 __attribute__((ext_vector_type(8)));
typedef float f32x4 __attribute__((ext_vector_type(4)));
typedef unsigned short u16;
typedef unsigned int u32;

static __device__ __forceinline__ u16 f2bf(float f) {
  u32 u = __builtin_bit_cast(u32, f);
  u32 r = (u + 0x7FFFu + ((u >> 16) & 1u)) >> 16;  // RNE
  return (u16)r;
}

// ---- kernel 0: one-time f32 -> bf16 weight conversion + FRAGMENT SWIZZLE ----
// Layout: chunk id = tile*512 + k*64 + lane; 16B chunk = W[tile*16 + (lane&15)]
//         [k*32 + (lane>>4)*8 .. +8].  wqkv: tiles 0..47 (tile = s*16+h*2+u).
//         wproj: tiles 0..15 with k=h.  wqkv_sw at wbf[0], wproj_sw at wbf[196608].
__global__ __launch_bounds__(256) void k_conv(
    const float* __restrict__ wqkv, const float* __restrict__ wproj,
    u16* __restrict__ wbf) {
  const int cid = blockIdx.x * 256 + threadIdx.x;  // 128 blocks -> 32768 chunks
  const float* src;
  if (cid < 24576) {  // qkv: tile = cid>>9
    const int tile = cid >> 9, rem = cid & 511;
    const int k = rem >> 6, lane = rem & 63;
    const int row = tile * 16 + (lane & 15), col = k * 32 + (lane >> 4) * 8;
    src = wqkv + (size_t)row * 256 + col;
  } else {            // proj
    const int pid = cid - 24576;
    const int mt = pid >> 9, rem = pid & 511;
    const int h = rem >> 6, lane = rem & 63;
    const int row = mt * 16 + (lane & 15), col = h * 32 + (lane >> 4) * 8;
    src = wproj + (size_t)row * 256 + col;
  }
  float4 f0 = *(const float4*)(src);
  float4 f1 = *(const float4*)(src + 4);
  ushort4 a, b;
  a.x = f2bf(f0.x); a.y = f2bf(f0.y); a.z = f2bf(f0.z); a.w = f2bf(f0.w);
  b.x = f2bf(f1.x); b.y = f2bf(f1.y); b.z = f2bf(f1.z); b.w = f2bf(f1.w);
  *(ushort4*)(wbf + (size_t)cid * 8) = a;
  *(ushort4*)(wbf + (size_t)cid * 8 + 4) = b;
}

// LDS (u16 units). X [64][264] = 16896 first; region reused per-head after
// A-frags are in registers:
//   QH=0: Qh [64][40] | KH=2560: Kh [64][40] | VTH=5120: VTh [32][72]
//   PH=7424: P per-wave [16][72] at PH + wv*1152
#define QH 0
#define KH 2560
#define VTH 5120
#define PH 7424
#define LDS_TOT 16896

__global__ __launch_bounds__(256, 3) void k_fused(
    const float* __restrict__ x, const u16* __restrict__ wbf,
    const int* __restrict__ shiftp, float* __restrict__ out) {
  __shared__ u16 LDS[LDS_TOT];
  // XCD-locality swizzle: the 8 windows sharing x/out cache lines (same b,wh)
  // get block IDs congruent mod 128 -> same XCD under round-robin dispatch.
  const int blk = blockIdx.x;
  const int win = ((blk & 127) << 3) | (blk >> 7);   // b*64 + wh*8 + ww
  const u16* wqkv_sw = wbf;             // swizzled [48 tiles][8 k][64 lane][8]
  const u16* wproj_sw = wbf + 196608;   // swizzled [16 tiles][8 h][64 lane][8]
  const int b = win >> 6, wh = (win >> 3) & 7, ww = win & 7;
  const int off = (shiftp[0] != 0) ? 4 : 0;
  const int t = threadIdx.x;

  // ---- phase 1: stage rolled X into LDS [pos][c] (f32 -> bf16) ----
  {
    u16* X = LDS;
    const int wr = t & 7;
    const int h = ((wh << 3) + wr + off) & 63;
    const int w0 = ((ww << 3) + off) & 63;   // 4-aligned -> no wrap inside run
    const int w1 = ((ww << 3) + off + 4) & 63;
    const int p0 = wr << 3;
    for (int it = 0; it < 8; ++it) {
      const int c = (t >> 3) + (it << 5);
      const float* src = x + ((size_t)(b * 256 + c) * 64 + h) * 64;
      float4 v0 = *(const float4*)(src + w0);
      float4 v1 = *(const float4*)(src + w1);
      X[(p0 + 0) * 264 + c] = f2bf(v0.x);
      X[(p0 + 1) * 264 + c] = f2bf(v0.y);
      X[(p0 + 2) * 264 + c] = f2bf(v0.z);
      X[(p0 + 3) * 264 + c] = f2bf(v0.w);
      X[(p0 + 4) * 264 + c] = f2bf(v1.x);
      X[(p0 + 5) * 264 + c] = f2bf(v1.y);
      X[(p0 + 6) * 264 + c] = f2bf(v1.z);
      X[(p0 + 7) * 264 + c] = f2bf(v1.w);
    }
  }
  __syncthreads();

  const int lane = t & 63, wv = t >> 6;  // wave wv owns pos rows wv*16..+15
  const int l15 = lane & 15, quad = lane >> 4;
  const int pos0 = wv * 16 + quad * 4;

  bf16x8 af[8];
#pragma unroll
  for (int k = 0; k < 8; ++k)
    af[k] = *(const bf16x8*)&LDS[(wv * 16 + l15) * 264 + quad * 8 + k * 32];
  __syncthreads();  // X dead; region reused below

  f32x4 accP[16];   // proj acc: tile mt rows quad*4+r (c_out), col l15 (pos)
#pragma unroll
  for (int mt = 0; mt < 16; ++mt) accP[mt] = (f32x4){0.f, 0.f, 0.f, 0.f};

  const float scale = 0.17677669529663687f;  // 1/sqrt(32)
  u16* Pw = LDS + PH + wv * 1152;            // per-wave P [16][72]

#pragma unroll 1
  for (int h = 0; h < 8; ++h) {
    // ---- QKV GEMM for this head (coalesced swizzled weight loads) ----
#pragma unroll
    for (int s = 0; s < 3; ++s) {
#pragma unroll
      for (int u = 0; u < 2; ++u) {
        const int tile = s * 16 + h * 2 + u;
        const u16* br = wqkv_sw + (size_t)tile * 4096 + lane * 8;
        f32x4 acc = {0.f, 0.f, 0.f, 0.f};
#pragma unroll
        for (int k = 0; k < 8; ++k)
          acc = __builtin_amdgcn_mfma_f32_16x16x32_bf16(
              af[k], *(const bf16x8*)(br + k * 512), acc, 0, 0, 0);
        if (s == 0) {
#pragma unroll
          for (int r = 0; r < 4; ++r)
            LDS[QH + (pos0 + r) * 40 + u * 16 + l15] = f2bf(acc[r]);
        } else if (s == 1) {
#pragma unroll
          for (int r = 0; r < 4; ++r)
            LDS[KH + (pos0 + r) * 40 + u * 16 + l15] = f2bf(acc[r]);
        } else {  // V transposed [hd][pos]
          ushort4 pk;
          pk.x = f2bf(acc[0]); pk.y = f2bf(acc[1]);
          pk.z = f2bf(acc[2]); pk.w = f2bf(acc[3]);
          *(ushort4*)&LDS[VTH + (u * 16 + l15) * 72 + pos0] = pk;
        }
      }
    }
    __syncthreads();  // Kh/VTh cross-wave visibility

    // ---- attention on own 16 pos rows ----
    bf16x8 aq = *(const bf16x8*)&LDS[QH + (wv * 16 + l15) * 40 + quad * 8];
    f32x4 sc[4];
#pragma unroll
    for (int nt = 0; nt < 4; ++nt) {
      bf16x8 bk = *(const bf16x8*)&LDS[KH + (nt * 16 + l15) * 40 + quad * 8];
      f32x4 z = {0.f, 0.f, 0.f, 0.f};
      sc[nt] = __builtin_amdgcn_mfma_f32_16x16x32_bf16(aq, bk, z, 0, 0, 0);
    }
#pragma unroll
    for (int r = 0; r < 4; ++r) {
      float mx = -1e30f;
#pragma unroll
      for (int nt = 0; nt < 4; ++nt) mx = fmaxf(mx, sc[nt][r]);
      mx = fmaxf(mx, __shfl_xor(mx, 1));
      mx = fmaxf(mx, __shfl_xor(mx, 2));
      mx = fmaxf(mx, __shfl_xor(mx, 4));
      mx = fmaxf(mx, __shfl_xor(mx, 8));  // row spans the 16-lane group
      float p[4], sum = 0.f;
#pragma unroll
      for (int nt = 0; nt < 4; ++nt) {
        p[nt] = __expf((sc[nt][r] - mx) * scale);
        sum += p[nt];
      }
      sum += __shfl_xor(sum, 1);
      sum += __shfl_xor(sum, 2);
      sum += __shfl_xor(sum, 4);
      sum += __shfl_xor(sum, 8);
      const float is = 1.f / sum;
#pragma unroll
      for (int nt = 0; nt < 4; ++nt)
        Pw[(quad * 4 + r) * 72 + nt * 16 + l15] = f2bf(p[nt] * is);
    }
    // PV
    f32x4 oa[2];
    oa[0] = (f32x4){0.f, 0.f, 0.f, 0.f};
    oa[1] = (f32x4){0.f, 0.f, 0.f, 0.f};
#pragma unroll
    for (int kk = 0; kk < 2; ++kk) {
      bf16x8 ap = *(const bf16x8*)&Pw[l15 * 72 + kk * 32 + quad * 8];
#pragma unroll
      for (int n2 = 0; n2 < 2; ++n2) {
        bf16x8 bv = *(const bf16x8*)&LDS[VTH + (n2 * 16 + l15) * 72 + kk * 32 + quad * 8];
        oa[n2] = __builtin_amdgcn_mfma_f32_16x16x32_bf16(ap, bv, oa[n2], 0, 0, 0);
      }
    }
    // O overwrites own Q rows (wave-private)
#pragma unroll
    for (int n2 = 0; n2 < 2; ++n2)
#pragma unroll
      for (int r = 0; r < 4; ++r)
        LDS[QH + (pos0 + r) * 40 + n2 * 16 + l15] = f2bf(oa[n2][r]);
    // proj accumulate: A = Wproj tile (swizzled, coalesced), B = O rows
    bf16x8 bo = *(const bf16x8*)&LDS[QH + (wv * 16 + l15) * 40 + quad * 8];
#pragma unroll
    for (int mt = 0; mt < 16; ++mt) {
      bf16x8 aw = *(const bf16x8*)(wproj_sw + (size_t)mt * 4096 + h * 512 + lane * 8);
      accP[mt] = __builtin_amdgcn_mfma_f32_16x16x32_bf16(aw, bo, accP[mt], 0, 0, 0);
    }
    __syncthreads();  // protect Kh/VTh before next head
  }

  // ---- epilogue: C[c_out][pos] -> out[b][c][h][w] with roll(+4,+4) ----
  const int pos = wv * 16 + l15;
  const int hco = ((wh << 3) + (pos >> 3) + off) & 63;
  const int wco = ((ww << 3) + (pos & 7) + off) & 63;
#pragma unroll
  for (int mt = 0; mt < 16; ++mt)
#pragma unroll
    for (int r = 0; r < 4; ++r) {
      const int c = mt * 16 + quad * 4 + r;
      out[((size_t)(b * 256 + c) << 12) + (hco << 6) + wco] = accP[mt][r];
    }
}

extern "C" void kernel_launch(void* const* d_in, const int* in_sizes, int n_in,
                              void* d_out, int out_size, void* d_ws, size_t ws_size,
                              hipStream_t stream) {
  const float* x = (const float*)d_in[0];      // [16,256,64,64] f32
  const float* wqkv = (const float*)d_in[1];   // [768,256] f32
  const float* wproj = (const float*)d_in[2];  // [256,256] f32
  const int* shiftp = (const int*)d_in[3];     // scalar
  float* outp = (float*)d_out;                 // [16,256,64,64] f32
  u16* wbf = (u16*)d_ws;                       // 262144 u16 = 512 KB scratch
  hipLaunchKernelGGL(k_conv, dim3(128), dim3(256), 0, stream, wqkv, wproj, wbf);
  hipLaunchKernelGGL(k_fused, dim3(1024), dim3(256), 0, stream, x, wbf, shiftp, outp);
}